// Round 3
// baseline (265.141 us; speedup 1.0000x reference)
//
#include <hip/hip_runtime.h>
#include <hip/hip_bf16.h>
#include <stdint.h>

#define BM 128
#define BN 128

typedef __attribute__((ext_vector_type(8))) short bf16x8;
typedef __attribute__((ext_vector_type(4))) float f32x4;
typedef __attribute__((ext_vector_type(4))) uint32_t u32x4;

__device__ __forceinline__ short f2bf(float f) {
  union { float f; uint32_t u; } v; v.f = f;
  return (short)((v.u + 0x7FFFu + ((v.u >> 16) & 1u)) >> 16);  // RNE
}
__device__ __forceinline__ float bf2f(uint16_t s) {
  union { uint32_t u; float f; } v; v.u = ((uint32_t)s) << 16;
  return v.f;
}
__device__ __forceinline__ uint32_t pk2(float lo, float hi) {
  union { __hip_bfloat162 h; uint32_t u; } un;
  un.h = __float22bfloat162_rn(make_float2(lo, hi));  // v_cvt_pk_bf16_f32
  return un.u;
}
__device__ __forceinline__ void gload_lds16(const void* g, void* l) {
  __builtin_amdgcn_global_load_lds((const __attribute__((address_space(1))) void*)g,
                                   (__attribute__((address_space(3))) void*)l, 16, 0, 0);
}

enum { A_LDS = 0, A_REG = 1, A_REGGATHER = 2 };
enum { E_PLAIN16 = 0, E_EDGE = 1, E_NODE = 2, E_PRED = 3 };

struct GemmArgs {
  const uint16_t* Ab; int lda;   // A_LDS: bf16 A
  const float* Af;               // A_REG*: fp32 A (lda=512)
  const int* gidx;               // row gather (A_REGGATHER)
  const uint16_t* B0;            // B^T bf16 [N][K]; out cols < 512
  const uint16_t* B1;            // out cols >= 512
  int K;
  uint16_t* C16; int ldc;        // bf16 output (E_PLAIN16 / E_NODE)
  const float* bias;
  const float* wattn;
  const int* src; const int* dst; const int* toe;
  const uint16_t* A13;           // bf16 [4096][1024]
  const uint16_t* U13;           // bf16 [4096][1024]
  uint16_t* EF;                  // e_f bf16 [61440][512]
  float* AATT;                   // attn partials [61440]
  float* OUT;                    // pred fp32 [3840][512]
};

template <int AMODE, int EPI>
__global__ __launch_bounds__(256) void gemm_k(GemmArgs g) {
  __shared__ __align__(16) short As[2][BM * 32];
  __shared__ __align__(16) short Bs[2][BN * 32];
  const int tid = threadIdx.x, w = tid >> 6, lane = tid & 63;
  const int m0 = blockIdx.x * BM, n0g = blockIdx.y * BN;

  const uint16_t* Bp = g.B0; int n0 = n0g;
  if (n0g >= 512) { Bp = g.B1; n0 = n0g - 512; }

  const int NT = g.K >> 5;

  // ---- global_load_lds geometry (16B/lane, linear dest) ----
  const int gr = lane >> 2, gk = (lane & 3) * 8;
  const uint16_t* gB0 = Bp + (size_t)(n0 + w * 16 + gr) * g.K + gk;
  const uint16_t* gB1 = gB0 + (size_t)64 * g.K;
  const int cofs0 = (w * 16) * 32;        // wave-uniform LDS short-offset
  const int cofs1 = (64 + w * 16) * 32;

  const uint16_t* gA0 = nullptr; const uint16_t* gA1 = nullptr;
  const float* arow = nullptr; int aofs = 0;
  if constexpr (AMODE == A_LDS) {
    gA0 = g.Ab + (size_t)(m0 + w * 16 + gr) * g.lda + gk;
    gA1 = gA0 + (size_t)64 * g.lda;
  } else {
    const int tr = tid >> 1, ch = tid & 1;
    int row = m0 + tr;
    if constexpr (AMODE == A_REGGATHER) row = g.gidx[row];
    arow = g.Af + (size_t)row * 512 + ch * 16;
    aofs = tr * 32 + ch * 16;
  }

  auto stageB = [&](int t, int buf) {
    gload_lds16(gB0 + t * 32, &Bs[buf][cofs0]);
    gload_lds16(gB1 + t * 32, &Bs[buf][cofs1]);
  };
  auto loadA = [&](float4* S, int t) {
    const float* p = arow + t * 32;
#pragma unroll
    for (int i = 0; i < 4; ++i) S[i] = *(const float4*)(p + i * 4);
  };
  auto writeA = [&](const float4* S, int buf) {
    u32x4 lo, hi;
    lo[0] = pk2(S[0].x, S[0].y); lo[1] = pk2(S[0].z, S[0].w);
    lo[2] = pk2(S[1].x, S[1].y); lo[3] = pk2(S[1].z, S[1].w);
    hi[0] = pk2(S[2].x, S[2].y); hi[1] = pk2(S[2].z, S[2].w);
    hi[2] = pk2(S[3].x, S[3].y); hi[3] = pk2(S[3].z, S[3].w);
    *(u32x4*)&As[buf][aofs] = lo;
    *(u32x4*)&As[buf][aofs + 8] = hi;
  };

  const int wm = w >> 1, wn = w & 1;
  const int lr = lane & 15, lg = lane >> 4;
  int aro[4], bro[4];
#pragma unroll
  for (int m = 0; m < 4; ++m) aro[m] = (wm * 64 + m * 16 + lr) * 32 + lg * 8;
#pragma unroll
  for (int n = 0; n < 4; ++n) bro[n] = (wn * 64 + n * 16 + lr) * 32 + lg * 8;

  f32x4 acc[4][4] = {};
  float4 Sa[4], Sb[4];

  // ---- prologue: stage tile 0 into buf0; prefetch A(1),A(2) to regs ----
  if constexpr (AMODE == A_LDS) {
    gload_lds16(gA0, &As[0][cofs0]);
    gload_lds16(gA1, &As[0][cofs1]);
    stageB(0, 0);
    asm volatile("s_waitcnt vmcnt(0)" ::: "memory");
    __builtin_amdgcn_s_barrier();
  } else {
    stageB(0, 0);                       // B first: in-order retirement covers it
    loadA(Sa, (NT > 1) ? 1 : 0);
    loadA(Sb, (NT > 2) ? 2 : 0);
    float4 T[4]; loadA(T, 0);
    writeA(T, 0);                       // compiler drains all prior VMEM here
    asm volatile("s_waitcnt lgkmcnt(0)" ::: "memory");
    __builtin_amdgcn_s_barrier();
  }

  for (int t = 0; t < NT; ++t) {
    const int cur = t & 1, nxt = cur ^ 1;
    const int tn = (t + 1 < NT) ? t + 1 : t;
    if constexpr (AMODE == A_LDS) {
      gload_lds16(gA0 + tn * 32, &As[nxt][cofs0]);
      gload_lds16(gA1 + tn * 32, &As[nxt][cofs1]);
      stageB(tn, nxt);
    } else {
      stageB(tn, nxt);                                   // 2 glds (oldest)
      if (t & 1) writeA(Sb, nxt); else writeA(Sa, nxt);  // A(t+1) -> LDS
      __builtin_amdgcn_sched_barrier(0);                 // keep glds before S loads
      const int tf = (t + 3 < NT) ? t + 3 : 0;
      if (t & 1) loadA(Sb, tf); else loadA(Sa, tf);      // 4 loads (newest)
    }
    bf16x8 av[4], bv[4];
#pragma unroll
    for (int m = 0; m < 4; ++m) av[m] = *(const bf16x8*)&As[cur][aro[m]];
#pragma unroll
    for (int n = 0; n < 4; ++n) bv[n] = *(const bf16x8*)&Bs[cur][bro[n]];
#pragma unroll
    for (int m = 0; m < 4; ++m)
#pragma unroll
      for (int n = 0; n < 4; ++n)
        acc[m][n] = __builtin_amdgcn_mfma_f32_16x16x32_bf16(av[m], bv[n], acc[m][n], 0, 0, 0);
    if constexpr (AMODE == A_LDS) {
      asm volatile("s_waitcnt vmcnt(0) lgkmcnt(0)" ::: "memory");
    } else {
      // outstanding: B(2)+this-iter A-prefetch(4); vmcnt(4) guarantees B done,
      // leaves the newest 4 A loads in flight across the barrier.
      asm volatile("s_waitcnt vmcnt(4) lgkmcnt(0)" ::: "memory");
    }
    __builtin_amdgcn_s_barrier();
  }

  // ---- epilogue ----  C/D: col = lane&15, row = (lane>>4)*4 + reg
  const int rbase = m0 + wm * 64;
  const int cbase = n0g + wn * 64;

  if constexpr (EPI == E_PLAIN16) {
#pragma unroll
    for (int m = 0; m < 4; ++m)
#pragma unroll
      for (int r = 0; r < 4; ++r) {
        const int row = rbase + m * 16 + lg * 4 + r;
#pragma unroll
        for (int n = 0; n < 4; ++n)
          g.C16[(size_t)row * g.ldc + cbase + n * 16 + lr] = (uint16_t)f2bf(acc[m][n][r]);
      }
  } else if constexpr (EPI == E_NODE) {
#pragma unroll
    for (int m = 0; m < 4; ++m)
#pragma unroll
      for (int r = 0; r < 4; ++r) {
        const int row = rbase + m * 16 + lg * 4 + r;
#pragma unroll
        for (int n = 0; n < 4; ++n) {
          const int col = cbase + n * 16 + lr;
          const float v = fmaxf(acc[m][n][r] + g.bias[col], 0.f);
          g.C16[(size_t)row * g.ldc + col] = (uint16_t)f2bf(v);
        }
      }
  } else if constexpr (EPI == E_EDGE) {
    float bv[4], wv[4]; int cols[4];
#pragma unroll
    for (int n = 0; n < 4; ++n) {
      cols[n] = cbase + n * 16 + lr;
      bv[n] = g.bias[cols[n]];
      wv[n] = g.wattn[cols[n]];
    }
#pragma unroll
    for (int m = 0; m < 4; ++m)
#pragma unroll
      for (int r = 0; r < 4; ++r) {
        const int e = rbase + m * 16 + lg * 4 + r;
        const int se = g.src[e], de = g.dst[e];
        const uint16_t* a1 = g.A13 + (size_t)se * 1024;
        const uint16_t* a3 = g.A13 + (size_t)de * 1024 + 512;
        float rp = 0.f;
#pragma unroll
        for (int n = 0; n < 4; ++n) {
          float v = acc[m][n][r] + bf2f(a1[cols[n]]) + bf2f(a3[cols[n]]) + bv[n];
          v = fmaxf(v, 0.f);
          rp += v * wv[n];
          g.EF[(size_t)e * 512 + cols[n]] = (uint16_t)f2bf(v);
        }
        for (int d = 1; d < 16; d <<= 1) rp += __shfl_xor(rp, d);
        if (lr == 0) atomicAdd(&g.AATT[e], rp);
      }
  } else {  // E_PRED
    float bv[4]; int cols[4];
#pragma unroll
    for (int n = 0; n < 4; ++n) { cols[n] = cbase + n * 16 + lr; bv[n] = g.bias[cols[n]]; }
#pragma unroll
    for (int m = 0; m < 4; ++m)
#pragma unroll
      for (int r = 0; r < 4; ++r) {
        const int row = rbase + m * 16 + lg * 4 + r;
        const int te = g.toe[row];
        const int ts = g.src[te], td = g.dst[te];
        const uint16_t* u1 = g.U13 + (size_t)ts * 1024;
        const uint16_t* u3 = g.U13 + (size_t)td * 1024 + 512;
#pragma unroll
        for (int n = 0; n < 4; ++n) {
          const float v = acc[m][n][r] + bf2f(u1[cols[n]]) + bf2f(u3[cols[n]]) + bv[n];
          g.OUT[(size_t)row * 512 + cols[n]] = fmaxf(v, 0.f);
        }
      }
  }
}

// ---------- visual fp32 -> bf16 (VISB) + prefill NIN[:,0:512] ----------
__global__ __launch_bounds__(256) void cvt_vis_k(const float* vis, uint16_t* VISB,
                                                 uint16_t* NIN) {
  const int idx = blockIdx.x * 256 + threadIdx.x;
  const int base = idx * 8;
  const int row = base >> 9, col = base & 511;
  const float4 f0 = *(const float4*)(vis + base);
  const float4 f1 = *(const float4*)(vis + base + 4);
  u32x4 u;
  u[0] = pk2(f0.x, f0.y); u[1] = pk2(f0.z, f0.w);
  u[2] = pk2(f1.x, f1.y); u[3] = pk2(f1.z, f1.w);
  *(u32x4*)(VISB + base) = u;
  *(u32x4*)(NIN + (size_t)row * 1024 + col) = u;
}

// ---------- weight transpose+convert: WT[n][k] = bf16(W[k][n]) ----------
__global__ __launch_bounds__(256) void trans_w_k(const float* We, const float* Wn,
                                                 const float* Wp, uint16_t* WT) {
  const int z = blockIdx.z;
  const float* src; uint16_t* dst; int ldo = 512, koff = 0;
  switch (z) {
    default:
    case 0: src = We;          dst = WT;           break;
    case 1: src = We + 262144; dst = WT + 262144;  break;
    case 2: src = We + 524288; dst = WT + 524288;  break;
    case 3: src = Wn;          dst = WT + 786432;  ldo = 1024; break;
    case 4: src = Wn + 262144; dst = WT + 786432;  ldo = 1024; koff = 512; break;
    case 5: src = Wp;          dst = WT + 1310720; break;
    case 6: src = Wp + 262144; dst = WT + 1572864; break;
    case 7: src = Wp + 524288; dst = WT + 1835008; break;
  }
  __shared__ float tile[32][33];
  const int tx = threadIdx.x, ty = threadIdx.y;  // 32 x 8
  const int kb = blockIdx.x * 32, nb = blockIdx.y * 32;
#pragma unroll
  for (int s = 0; s < 4; ++s)
    tile[ty + 8 * s][tx] = src[(size_t)(kb + ty + 8 * s) * 512 + nb + tx];
  __syncthreads();
#pragma unroll
  for (int s = 0; s < 4; ++s) {
    const int n = nb + ty + 8 * s, k = kb + tx;
    dst[(size_t)n * ldo + koff + k] = (uint16_t)f2bf(tile[tx][ty + 8 * s]);
  }
}

// ---------- softmax over 15 incoming edges + aggregate; writes NIN[:,512:] ----------
__global__ __launch_bounds__(256) void node_reduce_k(const float* AATT, const float* battn,
                                                     const uint16_t* EF, const uint16_t* VISB,
                                                     uint16_t* NIN) {
  const int sub = threadIdx.x >> 7;  // 2 nodes per block
  const int t = threadIdx.x & 127;
  const int v = blockIdx.x * 2 + sub;
  const int gph = v >> 4, j = v & 15;
  __shared__ float sa_s[2][16];
  __shared__ float alf_s[2][16];
  __shared__ int eids_s[2][16];
  __shared__ int srcs_s[2][16];
  if (t < 15) {
    const int i = (t < j) ? t : t + 1;
    const int off = (j < i) ? j : (j - 1);
    const int eid = gph * 240 + i * 15 + off;  // DGL src-major edge id
    eids_s[sub][t] = eid;
    srcs_s[sub][t] = gph * 16 + i;
    sa_s[sub][t] = fmaxf(AATT[eid] + battn[0], 0.f);
  }
  __syncthreads();
  float mx = -1e30f;
#pragma unroll
  for (int i = 0; i < 15; ++i) mx = fmaxf(mx, sa_s[sub][i]);
  float den = 0.f;
#pragma unroll
  for (int i = 0; i < 15; ++i) den += expf(sa_s[sub][i] - mx);
  if (t < 15) alf_s[sub][t] = expf(sa_s[sub][t] - mx) / den;
  __syncthreads();
  const int c = t * 4;
  float z0 = 0.f, z1 = 0.f, z2 = 0.f, z3 = 0.f;
#pragma unroll
  for (int i = 0; i < 15; ++i) {
    const float a = alf_s[sub][i];
    const ushort4 e4 = *(const ushort4*)(EF + (size_t)eids_s[sub][i] * 512 + c);
    const ushort4 v4 = *(const ushort4*)(VISB + (size_t)srcs_s[sub][i] * 512 + c);
    z0 += a * (bf2f(e4.x) + bf2f(v4.x)); z1 += a * (bf2f(e4.y) + bf2f(v4.y));
    z2 += a * (bf2f(e4.z) + bf2f(v4.z)); z3 += a * (bf2f(e4.w) + bf2f(v4.w));
  }
  ushort4 o;
  o.x = (unsigned short)f2bf(z0); o.y = (unsigned short)f2bf(z1);
  o.z = (unsigned short)f2bf(z2); o.w = (unsigned short)f2bf(z3);
  *(ushort4*)(NIN + (size_t)v * 1024 + 512 + c) = o;
}

// ---------------- launch ----------------
extern "C" void kernel_launch(void* const* d_in, const int* in_sizes, int n_in,
                              void* d_out, int out_size, void* d_ws, size_t ws_size,
                              hipStream_t stream) {
  const float* visual = (const float*)d_in[0];
  const float* spatial = (const float*)d_in[1];
  const float* W_edge = (const float*)d_in[2];
  const float* b_edge = (const float*)d_in[3];
  const float* W_attn = (const float*)d_in[4];
  const float* b_attn = (const float*)d_in[5];
  const float* W_node = (const float*)d_in[6];
  const float* b_node = (const float*)d_in[7];
  const float* W_pred = (const float*)d_in[8];
  const float* b_pred = (const float*)d_in[9];
  const int* src = (const int*)d_in[10];
  const int* dst = (const int*)d_in[11];
  const int* toe = (const int*)d_in[12];
  float* out = (float*)d_out;

  char* ws = (char*)d_ws;
  uint16_t* WT = (uint16_t*)ws;                    // @0        4 MB
  uint16_t* VISB = (uint16_t*)(ws + 4194304);      // @4MB      4 MB
  uint16_t* NIN = (uint16_t*)(ws + 8388608);       // @8MB      8 MB  [4096][1024]
  uint16_t* A13b = (uint16_t*)(ws + 16777216);     // @16MB     8 MB  [4096][1024]
  uint16_t* EF = (uint16_t*)(ws + 25165824);       // @24MB    60 MB  [61440][512]
  float* AATT = (float*)(ws + 88080384);           // @84MB   240 KB  (end 88,326,144)
  uint16_t* U13b = A13b;   // A13b dead after edge GEMM
  uint16_t* NNF = EF;      // EF dead after node_reduce

  cvt_vis_k<<<1024, 256, 0, stream>>>(visual, VISB, NIN);
  trans_w_k<<<dim3(16, 16, 8), dim3(32, 8), 0, stream>>>(W_edge, W_node, W_pred, WT);
  hipMemsetAsync(AATT, 0, 61440 * sizeof(float), stream);

  const dim3 blk(256);
  {  // A13 = vis_bf16 @ [W1 | W3]  (bf16 out)
    GemmArgs a = {};
    a.Ab = VISB; a.lda = 512; a.B0 = WT; a.B1 = WT + 524288; a.K = 512;
    a.C16 = A13b; a.ldc = 1024;
    gemm_k<A_LDS, E_PLAIN16><<<dim3(32, 8), blk, 0, stream>>>(a);
  }
  {  // e_f = relu(spatial@W2 + A1[src] + A3[dst] + b); attn partials
    GemmArgs a = {};
    a.Af = spatial; a.B0 = WT + 262144; a.K = 512;
    a.bias = b_edge; a.wattn = W_attn;
    a.src = src; a.dst = dst; a.A13 = A13b; a.EF = EF; a.AATT = AATT;
    gemm_k<A_REG, E_EDGE><<<dim3(480, 4), blk, 0, stream>>>(a);
  }
  node_reduce_k<<<2048, blk, 0, stream>>>(AATT, b_attn, EF, VISB, NIN);
  {  // new_n_f = relu(NIN @ W_node + b)  (K=1024)
    GemmArgs a = {};
    a.Ab = NIN; a.lda = 1024; a.B0 = WT + 786432; a.K = 1024;
    a.bias = b_node; a.C16 = NNF; a.ldc = 512;
    gemm_k<A_LDS, E_NODE><<<dim3(32, 4), blk, 0, stream>>>(a);
  }
  {  // U13 = new_n_f @ [Wp1 | Wp3]
    GemmArgs a = {};
    a.Ab = NNF; a.lda = 512; a.B0 = WT + 1310720; a.B1 = WT + 1835008; a.K = 512;
    a.C16 = U13b; a.ldc = 1024;
    gemm_k<A_LDS, E_PLAIN16><<<dim3(32, 8), blk, 0, stream>>>(a);
  }
  {  // pred = relu(U1[ts] + spatial[toe]@Wp2 + U3[td] + b)
    GemmArgs a = {};
    a.Af = spatial; a.gidx = toe; a.B0 = WT + 1572864; a.K = 512;
    a.bias = b_pred; a.toe = toe; a.src = src; a.dst = dst; a.U13 = U13b; a.OUT = out;
    gemm_k<A_REGGATHER, E_PRED><<<dim3(30, 4), blk, 0, stream>>>(a);
  }
  (void)in_sizes; (void)n_in; (void)out_size; (void)ws_size;
}

// Round 4
// 233.662 us; speedup vs baseline: 1.1347x; 1.1347x over previous
//
#include <hip/hip_runtime.h>
#include <hip/hip_bf16.h>
#include <stdint.h>

#define BM 128
#define BN 128

typedef __attribute__((ext_vector_type(8))) short bf16x8;
typedef __attribute__((ext_vector_type(4))) float f32x4;
typedef __attribute__((ext_vector_type(4))) uint32_t u32x4;

__device__ __forceinline__ short f2bf(float f) {
  union { float f; uint32_t u; } v; v.f = f;
  return (short)((v.u + 0x7FFFu + ((v.u >> 16) & 1u)) >> 16);  // RNE
}
__device__ __forceinline__ float bf2f(uint16_t s) {
  union { uint32_t u; float f; } v; v.u = ((uint32_t)s) << 16;
  return v.f;
}
__device__ __forceinline__ uint32_t pk2(float lo, float hi) {
  union { __hip_bfloat162 h; uint32_t u; } un;
  un.h = __float22bfloat162_rn(make_float2(lo, hi));  // v_cvt_pk_bf16_f32
  return un.u;
}
__device__ __forceinline__ void gload_lds16(const void* g, void* l) {
  __builtin_amdgcn_global_load_lds((const __attribute__((address_space(1))) void*)g,
                                   (__attribute__((address_space(3))) void*)l, 16, 0, 0);
}
// bijective XCD-chunk swizzle (m204): consecutive sids land on the same XCD chunk
__device__ __forceinline__ int xcd_swz(int d, int n) {
  const int q = n >> 3, r = n & 7, x = d & 7, i = d >> 3;
  return (x < r ? x * (q + 1) : r * (q + 1) + (x - r) * q) + i;
}

enum { A_LDS = 0, A_REG = 1, A_REGGATHER = 2 };
enum { E_PLAIN16 = 0, E_EDGE = 1, E_NODE = 2, E_PRED = 3 };

struct GemmArgs {
  const uint16_t* Ab; int lda;   // A_LDS: bf16 A
  const float* Af;               // A_REG*: fp32 A (lda=512)
  const int* gidx;               // row gather (A_REGGATHER)
  const uint16_t* B0;            // B^T bf16 [N][K]; out cols < 512
  const uint16_t* B1;            // out cols >= 512
  int K;
  int nwg, ncol;                 // 1-D grid decomposition (col-fastest after swizzle)
  uint16_t* C16; int ldc;        // bf16 output
  const float* bias;
  const float* wattn;
  const int* src; const int* dst; const int* toe;
  const uint16_t* A13;           // bf16 [4096][1024]
  const uint16_t* U13;           // bf16 [4096][1024]
  uint16_t* EF;                  // e_f bf16 [61440][512]
  float* AATT;                   // attn partials [61440]
  float* OUT;                    // pred fp32 [3840][512]
};

template <int AMODE, int EPI>
__global__ __launch_bounds__(256) void gemm_k(GemmArgs g) {
  __shared__ __align__(16) short As[2][BM * 32];
  __shared__ __align__(16) short Bs[2][BN * 32];
  const int tid = threadIdx.x, w = tid >> 6, lane = tid & 63;

  const int sid = xcd_swz(blockIdx.x, g.nwg);
  const int colb = sid % g.ncol, rowb = sid / g.ncol;
  const int m0 = rowb * BM, n0g = colb * BN;

  const uint16_t* Bp = g.B0; int n0 = n0g;
  if (n0g >= 512) { Bp = g.B1; n0 = n0g - 512; }

  // ---- global_load_lds geometry (16B/lane, linear dest) ----
  const int gr = lane >> 2, gk = (lane & 3) * 8;
  const uint16_t* gB0 = Bp + (size_t)(n0 + w * 16 + gr) * g.K + gk;
  const uint16_t* gB1 = gB0 + (size_t)64 * g.K;
  const int cofs0 = (w * 16) * 32;        // wave-uniform LDS short-offset
  const int cofs1 = (64 + w * 16) * 32;

  const uint16_t* gA0 = nullptr; const uint16_t* gA1 = nullptr;
  const float* arow = nullptr; int aofs = 0;
  if constexpr (AMODE == A_LDS) {
    gA0 = g.Ab + (size_t)(m0 + w * 16 + gr) * g.lda + gk;
    gA1 = gA0 + (size_t)64 * g.lda;
  } else {
    const int tr = tid >> 1, ch = tid & 1;
    int row = m0 + tr;
    if constexpr (AMODE == A_REGGATHER) row = g.gidx[row];
    arow = g.Af + (size_t)row * 512 + ch * 16;
    aofs = tr * 32 + ch * 16;
  }

  const int wm = w >> 1, wn = w & 1;
  const int lr = lane & 15, lg = lane >> 4;
  int aro[4], bro[4];
#pragma unroll
  for (int m = 0; m < 4; ++m) aro[m] = (wm * 64 + m * 16 + lr) * 32 + lg * 8;
#pragma unroll
  for (int n = 0; n < 4; ++n) bro[n] = (wn * 64 + n * 16 + lr) * 32 + lg * 8;

  f32x4 acc[4][4] = {};

  for (int k0 = 0; k0 < g.K; k0 += 64) {
    __syncthreads();
    // B first: direct-to-LDS, in flight longest
#pragma unroll
    for (int h = 0; h < 2; ++h) {
      const int kk = k0 + h * 32;
      gload_lds16(gB0 + kk, &Bs[h][cofs0]);
      gload_lds16(gB1 + kk, &Bs[h][cofs1]);
    }
#pragma unroll
    for (int h = 0; h < 2; ++h) {
      const int kk = k0 + h * 32;
      if constexpr (AMODE == A_LDS) {
        gload_lds16(gA0 + kk, &As[h][cofs0]);
        gload_lds16(gA1 + kk, &As[h][cofs1]);
      } else {
        const float* p = arow + kk;
        const float4 f0 = *(const float4*)(p);
        const float4 f1 = *(const float4*)(p + 4);
        const float4 f2 = *(const float4*)(p + 8);
        const float4 f3 = *(const float4*)(p + 12);
        u32x4 lo, hi;
        lo[0] = pk2(f0.x, f0.y); lo[1] = pk2(f0.z, f0.w);
        lo[2] = pk2(f1.x, f1.y); lo[3] = pk2(f1.z, f1.w);
        hi[0] = pk2(f2.x, f2.y); hi[1] = pk2(f2.z, f2.w);
        hi[2] = pk2(f3.x, f3.y); hi[3] = pk2(f3.z, f3.w);
        *(u32x4*)&As[h][aofs] = lo;
        *(u32x4*)&As[h][aofs + 8] = hi;
      }
    }
    __syncthreads();
#pragma unroll
    for (int h = 0; h < 2; ++h) {
      bf16x8 av[4], bv[4];
#pragma unroll
      for (int m = 0; m < 4; ++m) av[m] = *(const bf16x8*)&As[h][aro[m]];
#pragma unroll
      for (int n = 0; n < 4; ++n) bv[n] = *(const bf16x8*)&Bs[h][bro[n]];
#pragma unroll
      for (int m = 0; m < 4; ++m)
#pragma unroll
        for (int n = 0; n < 4; ++n)
          acc[m][n] = __builtin_amdgcn_mfma_f32_16x16x32_bf16(av[m], bv[n], acc[m][n], 0, 0, 0);
    }
  }

  // ---- epilogue ----  C/D: col = lane&15, row = (lane>>4)*4 + reg
  const int rbase = m0 + wm * 64;
  const int cbase = n0g + wn * 64;

  if constexpr (EPI == E_PLAIN16) {
#pragma unroll
    for (int m = 0; m < 4; ++m)
#pragma unroll
      for (int r = 0; r < 4; ++r) {
        const int row = rbase + m * 16 + lg * 4 + r;
#pragma unroll
        for (int n = 0; n < 4; ++n)
          g.C16[(size_t)row * g.ldc + cbase + n * 16 + lr] = (uint16_t)f2bf(acc[m][n][r]);
      }
  } else if constexpr (EPI == E_NODE) {
#pragma unroll
    for (int m = 0; m < 4; ++m)
#pragma unroll
      for (int r = 0; r < 4; ++r) {
        const int row = rbase + m * 16 + lg * 4 + r;
#pragma unroll
        for (int n = 0; n < 4; ++n) {
          const int col = cbase + n * 16 + lr;
          const float v = fmaxf(acc[m][n][r] + g.bias[col], 0.f);
          g.C16[(size_t)row * g.ldc + col] = (uint16_t)f2bf(v);
        }
      }
  } else if constexpr (EPI == E_EDGE) {
    float bv[4], wv[4]; int cols[4];
#pragma unroll
    for (int n = 0; n < 4; ++n) {
      cols[n] = cbase + n * 16 + lr;
      bv[n] = g.bias[cols[n]];
      wv[n] = g.wattn[cols[n]];
    }
#pragma unroll
    for (int m = 0; m < 4; ++m)
#pragma unroll
      for (int r = 0; r < 4; ++r) {
        const int e = rbase + m * 16 + lg * 4 + r;
        const int se = g.src[e], de = g.dst[e];
        const uint16_t* a1 = g.A13 + (size_t)se * 1024;
        const uint16_t* a3 = g.A13 + (size_t)de * 1024 + 512;
        float rp = 0.f;
#pragma unroll
        for (int n = 0; n < 4; ++n) {
          float v = acc[m][n][r] + bf2f(a1[cols[n]]) + bf2f(a3[cols[n]]) + bv[n];
          v = fmaxf(v, 0.f);
          rp += v * wv[n];
          g.EF[(size_t)e * 512 + cols[n]] = (uint16_t)f2bf(v);
        }
        for (int d = 1; d < 16; d <<= 1) rp += __shfl_xor(rp, d);
        if (lr == 0) atomicAdd(&g.AATT[e], rp);
      }
  } else {  // E_PRED
    float bv[4]; int cols[4];
#pragma unroll
    for (int n = 0; n < 4; ++n) { cols[n] = cbase + n * 16 + lr; bv[n] = g.bias[cols[n]]; }
#pragma unroll
    for (int m = 0; m < 4; ++m)
#pragma unroll
      for (int r = 0; r < 4; ++r) {
        const int row = rbase + m * 16 + lg * 4 + r;
        const int te = g.toe[row];
        const int ts = g.src[te], td = g.dst[te];
        const uint16_t* u1 = g.U13 + (size_t)ts * 1024;
        const uint16_t* u3 = g.U13 + (size_t)td * 1024 + 512;
#pragma unroll
        for (int n = 0; n < 4; ++n) {
          const float v = acc[m][n][r] + bf2f(u1[cols[n]]) + bf2f(u3[cols[n]]) + bv[n];
          g.OUT[(size_t)row * 512 + cols[n]] = fmaxf(v, 0.f);
        }
      }
  }
}

// ---------- visual fp32 -> bf16 (VISB) + prefill NIN[:,0:512] ----------
__global__ __launch_bounds__(256) void cvt_vis_k(const float* vis, uint16_t* VISB,
                                                 uint16_t* NIN) {
  const int idx = blockIdx.x * 256 + threadIdx.x;
  const int base = idx * 8;
  const int row = base >> 9, col = base & 511;
  const float4 f0 = *(const float4*)(vis + base);
  const float4 f1 = *(const float4*)(vis + base + 4);
  u32x4 u;
  u[0] = pk2(f0.x, f0.y); u[1] = pk2(f0.z, f0.w);
  u[2] = pk2(f1.x, f1.y); u[3] = pk2(f1.z, f1.w);
  *(u32x4*)(VISB + base) = u;
  *(u32x4*)(NIN + (size_t)row * 1024 + col) = u;
}

// ---------- weight transpose+convert: WT[n][k] = bf16(W[k][n]) ----------
__global__ __launch_bounds__(256) void trans_w_k(const float* We, const float* Wn,
                                                 const float* Wp, uint16_t* WT) {
  const int z = blockIdx.z;
  const float* src; uint16_t* dst; int ldo = 512, koff = 0;
  switch (z) {
    default:
    case 0: src = We;          dst = WT;           break;
    case 1: src = We + 262144; dst = WT + 262144;  break;
    case 2: src = We + 524288; dst = WT + 524288;  break;
    case 3: src = Wn;          dst = WT + 786432;  ldo = 1024; break;
    case 4: src = Wn + 262144; dst = WT + 786432;  ldo = 1024; koff = 512; break;
    case 5: src = Wp;          dst = WT + 1310720; break;
    case 6: src = Wp + 262144; dst = WT + 1572864; break;
    case 7: src = Wp + 524288; dst = WT + 1835008; break;
  }
  __shared__ float tile[32][33];
  const int tx = threadIdx.x, ty = threadIdx.y;  // 32 x 8
  const int kb = blockIdx.x * 32, nb = blockIdx.y * 32;
#pragma unroll
  for (int s = 0; s < 4; ++s)
    tile[ty + 8 * s][tx] = src[(size_t)(kb + ty + 8 * s) * 512 + nb + tx];
  __syncthreads();
#pragma unroll
  for (int s = 0; s < 4; ++s) {
    const int n = nb + ty + 8 * s, k = kb + tx;
    dst[(size_t)n * ldo + koff + k] = (uint16_t)f2bf(tile[tx][ty + 8 * s]);
  }
}

// ---------- softmax over 15 incoming edges + aggregate; writes NIN[:,512:] ----------
__global__ __launch_bounds__(256) void node_reduce_k(const float* AATT, const float* battn,
                                                     const uint16_t* EF, const uint16_t* VISB,
                                                     uint16_t* NIN) {
  const int sub = threadIdx.x >> 7;  // 2 nodes per block
  const int t = threadIdx.x & 127;
  const int v = blockIdx.x * 2 + sub;
  const int gph = v >> 4, j = v & 15;
  __shared__ float sa_s[2][16];
  __shared__ float alf_s[2][16];
  __shared__ int eids_s[2][16];
  __shared__ int srcs_s[2][16];
  if (t < 15) {
    const int i = (t < j) ? t : t + 1;
    const int off = (j < i) ? j : (j - 1);
    const int eid = gph * 240 + i * 15 + off;  // DGL src-major edge id
    eids_s[sub][t] = eid;
    srcs_s[sub][t] = gph * 16 + i;
    sa_s[sub][t] = fmaxf(AATT[eid] + battn[0], 0.f);
  }
  __syncthreads();
  float mx = -1e30f;
#pragma unroll
  for (int i = 0; i < 15; ++i) mx = fmaxf(mx, sa_s[sub][i]);
  float den = 0.f;
#pragma unroll
  for (int i = 0; i < 15; ++i) den += expf(sa_s[sub][i] - mx);
  if (t < 15) alf_s[sub][t] = expf(sa_s[sub][t] - mx) / den;
  __syncthreads();
  const int c = t * 4;
  float z0 = 0.f, z1 = 0.f, z2 = 0.f, z3 = 0.f;
#pragma unroll
  for (int i = 0; i < 15; ++i) {
    const float a = alf_s[sub][i];
    const ushort4 e4 = *(const ushort4*)(EF + (size_t)eids_s[sub][i] * 512 + c);
    const ushort4 v4 = *(const ushort4*)(VISB + (size_t)srcs_s[sub][i] * 512 + c);
    z0 += a * (bf2f(e4.x) + bf2f(v4.x)); z1 += a * (bf2f(e4.y) + bf2f(v4.y));
    z2 += a * (bf2f(e4.z) + bf2f(v4.z)); z3 += a * (bf2f(e4.w) + bf2f(v4.w));
  }
  ushort4 o;
  o.x = (unsigned short)f2bf(z0); o.y = (unsigned short)f2bf(z1);
  o.z = (unsigned short)f2bf(z2); o.w = (unsigned short)f2bf(z3);
  *(ushort4*)(NIN + (size_t)v * 1024 + 512 + c) = o;
}

// ---------------- launch ----------------
extern "C" void kernel_launch(void* const* d_in, const int* in_sizes, int n_in,
                              void* d_out, int out_size, void* d_ws, size_t ws_size,
                              hipStream_t stream) {
  const float* visual = (const float*)d_in[0];
  const float* spatial = (const float*)d_in[1];
  const float* W_edge = (const float*)d_in[2];
  const float* b_edge = (const float*)d_in[3];
  const float* W_attn = (const float*)d_in[4];
  const float* b_attn = (const float*)d_in[5];
  const float* W_node = (const float*)d_in[6];
  const float* b_node = (const float*)d_in[7];
  const float* W_pred = (const float*)d_in[8];
  const float* b_pred = (const float*)d_in[9];
  const int* src = (const int*)d_in[10];
  const int* dst = (const int*)d_in[11];
  const int* toe = (const int*)d_in[12];
  float* out = (float*)d_out;

  char* ws = (char*)d_ws;
  uint16_t* WT = (uint16_t*)ws;                    // @0        4 MB
  uint16_t* VISB = (uint16_t*)(ws + 4194304);      // @4MB      4 MB
  uint16_t* NIN = (uint16_t*)(ws + 8388608);       // @8MB      8 MB  [4096][1024]
  uint16_t* A13b = (uint16_t*)(ws + 16777216);     // @16MB     8 MB  [4096][1024]
  uint16_t* EF = (uint16_t*)(ws + 25165824);       // @24MB    60 MB  [61440][512]
  float* AATT = (float*)(ws + 88080384);           // @84MB   240 KB  (end 88,326,144)
  uint16_t* U13b = A13b;   // A13b dead after edge GEMM
  uint16_t* NNF = EF;      // EF dead after node_reduce

  cvt_vis_k<<<1024, 256, 0, stream>>>(visual, VISB, NIN);
  trans_w_k<<<dim3(16, 16, 8), dim3(32, 8), 0, stream>>>(W_edge, W_node, W_pred, WT);
  hipMemsetAsync(AATT, 0, 61440 * sizeof(float), stream);

  const dim3 blk(256);
  {  // A13 = vis_bf16 @ [W1 | W3]  (bf16 out)
    GemmArgs a = {};
    a.Ab = VISB; a.lda = 512; a.B0 = WT; a.B1 = WT + 524288; a.K = 512;
    a.nwg = 256; a.ncol = 8;
    a.C16 = A13b; a.ldc = 1024;
    gemm_k<A_LDS, E_PLAIN16><<<256, blk, 0, stream>>>(a);
  }
  {  // e_f = relu(spatial@W2 + A1[src] + A3[dst] + b); attn partials
    GemmArgs a = {};
    a.Af = spatial; a.B0 = WT + 262144; a.K = 512;
    a.nwg = 1920; a.ncol = 4;
    a.bias = b_edge; a.wattn = W_attn;
    a.src = src; a.dst = dst; a.A13 = A13b; a.EF = EF; a.AATT = AATT;
    gemm_k<A_REG, E_EDGE><<<1920, blk, 0, stream>>>(a);
  }
  node_reduce_k<<<2048, blk, 0, stream>>>(AATT, b_attn, EF, VISB, NIN);
  {  // new_n_f = relu(NIN @ W_node + b)  (K=1024)
    GemmArgs a = {};
    a.Ab = NIN; a.lda = 1024; a.B0 = WT + 786432; a.K = 1024;
    a.nwg = 128; a.ncol = 4;
    a.bias = b_node; a.C16 = NNF; a.ldc = 512;
    gemm_k<A_LDS, E_NODE><<<128, blk, 0, stream>>>(a);
  }
  {  // U13 = new_n_f @ [Wp1 | Wp3]
    GemmArgs a = {};
    a.Ab = NNF; a.lda = 512; a.B0 = WT + 1310720; a.B1 = WT + 1835008; a.K = 512;
    a.nwg = 256; a.ncol = 8;
    a.C16 = U13b; a.ldc = 1024;
    gemm_k<A_LDS, E_PLAIN16><<<256, blk, 0, stream>>>(a);
  }
  {  // pred = relu(U1[ts] + spatial[toe]@Wp2 + U3[td] + b)
    GemmArgs a = {};
    a.Af = spatial; a.gidx = toe; a.B0 = WT + 1572864; a.K = 512;
    a.nwg = 120; a.ncol = 4;
    a.bias = b_pred; a.toe = toe; a.src = src; a.dst = dst; a.U13 = U13b; a.OUT = out;
    gemm_k<A_REGGATHER, E_PRED><<<120, blk, 0, stream>>>(a);
  }
  (void)in_sizes; (void)n_in; (void)out_size; (void)ws_size;
}